// Round 5
// baseline (499.988 us; speedup 1.0000x reference)
//
#include <hip/hip_runtime.h>
#include <hip/hip_bf16.h>
#include <stdint.h>

#define N_NODES 100000
#define IN_F    512
#define OUT_F   256
#define N_EDGES 1600000

typedef __attribute__((ext_vector_type(4))) float f32x4;
typedef __attribute__((ext_vector_type(8))) short bf16x8;
typedef __attribute__((ext_vector_type(4))) uint32_t u32x4;

#define BM 128
#define BK 32
#define KT_TILES (IN_F / BK)             // 16
#define WFRAG_KT_STRIDE (16 * 16 * 32)   // 8192 elems per kt slab

#define SCAN_CHUNK 4096
#define NCHUNKS ((N_NODES + SCAN_CHUNK - 1) / SCAN_CHUNK)   // 25

__device__ __forceinline__ float bf2f(uint16_t u) {
    union { uint32_t i; float f; } c; c.i = ((uint32_t)u) << 16; return c.f;
}
__device__ __forceinline__ uint16_t f2bf(float f) {
    union { float f; uint32_t i; } c; c.f = f;
    uint32_t x = c.i;
    return (uint16_t)((x + 0x7FFFu + ((x >> 16) & 1u)) >> 16);  // RNE
}
__device__ __forceinline__ uint32_t cvt_pk_bf16(float a, float b) {
    uint32_t r;
    asm("v_cvt_pk_bf16_f32 %0, %1, %2" : "=v"(r) : "v"(a), "v"(b));
    return r;
}

// ---------------- W -> bf16 fragment-order ----------------
// w_frag[((kt*16 + cg)*16 + lrow)*32 + kg*8 + j] = bf16(W[cg*16+lrow][kt*32+kg*8+j])
__global__ __launch_bounds__(256) void w_frag_kernel(
    const float* __restrict__ W, uint16_t* __restrict__ w_frag)
{
    const int gid = blockIdx.x * 256 + threadIdx.x;   // 16384 groups of 8 elems
    if (gid >= 16384) return;
    const int kg = gid & 3, lrow = (gid >> 2) & 15, cg = (gid >> 6) & 15, kt = gid >> 10;
    const float* s = W + (size_t)(cg * 16 + lrow) * IN_F + kt * 32 + kg * 8;
    const f32x4 v0 = *(const f32x4*)s;
    const f32x4 v1 = *(const f32x4*)(s + 4);
    u32x4 c;
    c[0] = cvt_pk_bf16(v0[0], v0[1]);
    c[1] = cvt_pk_bf16(v0[2], v0[3]);
    c[2] = cvt_pk_bf16(v1[0], v1[1]);
    c[3] = cvt_pk_bf16(v1[2], v1[3]);
    *(u32x4*)(w_frag + (size_t)gid * 8) = c;
}

// ---------------- GEMM: h = bf16(feat @ W^T + b) ----------------
// Barrier-free, LDS-free: each lane loads its MFMA A-fragment elements
// directly from global fp32 (A layout: row=lane&15, k=(lane>>4)*8+j),
// converts via v_cvt_pk_bf16_f32; B comes pre-fragmented from w_frag.
// Even/odd register double-buffer, static indexing, no __syncthreads.
__global__ __launch_bounds__(256) void gcn_gemm_kernel(
    const float* __restrict__ feat, const uint16_t* __restrict__ w_frag,
    const float* __restrict__ bias, uint16_t* __restrict__ h)
{
    const int bid = blockIdx.x;
    const int mt = bid >> 1;
    const int nt = bid & 1;
    const int m0 = mt * BM;

    const int t    = threadIdx.x;
    const int wid  = t >> 6;
    const int lane = t & 63;
    const int wr   = wid >> 1, wc = wid & 1;   // 2x2 waves, 64x64 tile per wave
    const int lrow = lane & 15;
    const int kg   = lane >> 4;

    f32x4 acc[4][4] = {};

    // A addresses: frag m -> row m0 + wr*64 + m*16 + lrow, k-base kg*8
    const float* ga[4];
    bool aok[4];
    #pragma unroll
    for (int m = 0; m < 4; ++m) {
        const int row = m0 + wr * 64 + m * 16 + lrow;
        aok[m] = row < N_NODES;
        ga[m] = feat + (size_t)(aok[m] ? row : 0) * IN_F + kg * 8;
    }
    // B fragment pointers
    const uint16_t* wfp[4];
    #pragma unroll
    for (int n = 0; n < 4; ++n) {
        const int cg = nt * 8 + wc * 4 + n;
        wfp[n] = w_frag + ((size_t)cg * 16 + lrow) * 32 + kg * 8;
    }

    const f32x4 zero = {0.f, 0.f, 0.f, 0.f};

#define LOAD_TILES(AV, BV, KT)                                            \
    do {                                                                  \
        _Pragma("unroll")                                                 \
        for (int m_ = 0; m_ < 4; ++m_) {                                  \
            const f32x4* p_ = (const f32x4*)(ga[m_] + (KT) * BK);         \
            AV[2*m_]   = aok[m_] ? p_[0] : zero;                          \
            AV[2*m_+1] = aok[m_] ? p_[1] : zero;                          \
        }                                                                 \
        _Pragma("unroll")                                                 \
        for (int n_ = 0; n_ < 4; ++n_)                                    \
            BV[n_] = *(const bf16x8*)(wfp[n_] + (size_t)(KT) * WFRAG_KT_STRIDE); \
    } while (0)

#define COMPUTE_TILES(AV, BV)                                             \
    do {                                                                  \
        bf16x8 af_[4];                                                    \
        _Pragma("unroll")                                                 \
        for (int m_ = 0; m_ < 4; ++m_) {                                  \
            union { bf16x8 v; uint32_t u[4]; } c_;                        \
            c_.u[0] = cvt_pk_bf16(AV[2*m_][0],   AV[2*m_][1]);            \
            c_.u[1] = cvt_pk_bf16(AV[2*m_][2],   AV[2*m_][3]);            \
            c_.u[2] = cvt_pk_bf16(AV[2*m_+1][0], AV[2*m_+1][1]);          \
            c_.u[3] = cvt_pk_bf16(AV[2*m_+1][2], AV[2*m_+1][3]);          \
            af_[m_] = c_.v;                                               \
        }                                                                 \
        _Pragma("unroll")                                                 \
        for (int m_ = 0; m_ < 4; ++m_)                                    \
            _Pragma("unroll")                                             \
            for (int n_ = 0; n_ < 4; ++n_)                                \
                acc[m_][n_] = __builtin_amdgcn_mfma_f32_16x16x32_bf16(    \
                    af_[m_], BV[n_], acc[m_][n_], 0, 0, 0);               \
    } while (0)

    f32x4 aE[8], aO[8];
    bf16x8 bE[4], bO[4];
    LOAD_TILES(aE, bE, 0);
    LOAD_TILES(aO, bO, 1);

    #pragma unroll
    for (int kt = 0; kt < KT_TILES; kt += 2) {
        COMPUTE_TILES(aE, bE);
        if (kt + 2 < KT_TILES) LOAD_TILES(aE, bE, kt + 2);
        COMPUTE_TILES(aO, bO);
        if (kt + 3 < KT_TILES) LOAD_TILES(aO, bO, kt + 3);
    }
#undef LOAD_TILES
#undef COMPUTE_TILES

    // ---- epilogue: bias + bf16 store ----
    #pragma unroll
    for (int n = 0; n < 4; ++n) {
        const int col = nt * 128 + wc * 64 + n * 16 + lrow;
        const float bv = bias[col];
        #pragma unroll
        for (int m = 0; m < 4; ++m) {
            #pragma unroll
            for (int j = 0; j < 4; ++j) {
                const int row = m0 + wr * 64 + m * 16 + kg * 4 + j;
                if (row < N_NODES)
                    h[(size_t)row * OUT_F + col] = f2bf(acc[m][n][j] + bv);
            }
        }
    }
}

// ---------------- CSR build ----------------
__global__ __launch_bounds__(256) void hist_kernel(
    const int* __restrict__ dst, int* __restrict__ deg)
{
    const int e = blockIdx.x * 256 + threadIdx.x;
    if (e < N_EDGES) atomicAdd(&deg[dst[e]], 1);
}

__global__ __launch_bounds__(256) void chunk_reduce_kernel(
    const int* __restrict__ deg, int* __restrict__ chunkSum)
{
    __shared__ int red[256];
    const int b = blockIdx.x, t = threadIdx.x;
    const int base = b * SCAN_CHUNK;
    int s = 0;
    #pragma unroll
    for (int i = 0; i < 16; ++i) {
        const int idx = base + t * 16 + i;
        s += (idx < N_NODES) ? deg[idx] : 0;
    }
    red[t] = s;
    __syncthreads();
    for (int off = 128; off > 0; off >>= 1) {
        if (t < off) red[t] += red[t + off];
        __syncthreads();
    }
    if (t == 0) chunkSum[b] = red[0];
}

__global__ void scan_chunksums_kernel(const int* __restrict__ chunkSum,
                                      int* __restrict__ chunkOff)
{
    if (threadIdx.x == 0 && blockIdx.x == 0) {
        int acc = 0;
        for (int i = 0; i < NCHUNKS; ++i) { chunkOff[i] = acc; acc += chunkSum[i]; }
    }
}

__global__ __launch_bounds__(256) void chunk_scan_kernel(
    const int* __restrict__ deg, const int* __restrict__ chunkOff,
    int* __restrict__ start, int* __restrict__ cursor)
{
    __shared__ int tsum[256];
    const int b = blockIdx.x, t = threadIdx.x;
    const int base = b * SCAN_CHUNK;
    int vals[16];
    int s = 0;
    #pragma unroll
    for (int i = 0; i < 16; ++i) {
        const int idx = base + t * 16 + i;
        const int v = (idx < N_NODES) ? deg[idx] : 0;
        vals[i] = s;
        s += v;
    }
    int x = s;
    tsum[t] = x;
    __syncthreads();
    #pragma unroll
    for (int off = 1; off < 256; off <<= 1) {
        const int y = (t >= off) ? tsum[t - off] : 0;
        __syncthreads();
        x += y;
        tsum[t] = x;
        __syncthreads();
    }
    const int thread_off = chunkOff[b] + (t == 0 ? 0 : tsum[t - 1]);
    #pragma unroll
    for (int i = 0; i < 16; ++i) {
        const int idx = base + t * 16 + i;
        if (idx < N_NODES) {
            const int st = thread_off + vals[i];
            start[idx] = st;
            cursor[idx] = st;
        }
    }
}

__global__ __launch_bounds__(256) void csr_fill_kernel(
    const int* __restrict__ src, const int* __restrict__ dst,
    int* __restrict__ cursor, int* __restrict__ csr_src)
{
    const int e = blockIdx.x * 256 + threadIdx.x;
    if (e < N_EDGES) {
        const int d = dst[e];
        const int p = atomicAdd(&cursor[d], 1);
        csr_src[p] = src[e];
    }
}

// ---------------- gather: one wave per dst node, atomic-free ----------------
__global__ __launch_bounds__(256) void gcn_gather_kernel(
    const uint16_t* __restrict__ h, const int* __restrict__ start,
    const int* __restrict__ csr_src, float* __restrict__ out)
{
    const int n = blockIdx.x * 4 + (threadIdx.x >> 6);
    if (n >= N_NODES) return;
    const int lane = threadIdx.x & 63;
    const int beg = start[n];
    const int end = (n == N_NODES - 1) ? N_EDGES : start[n + 1];

    float a0 = 0.f, a1 = 0.f, a2 = 0.f, a3 = 0.f;
    int j = beg;
    for (; j + 1 < end; j += 2) {
        const int s0 = csr_src[j];
        const int s1 = csr_src[j + 1];
        const ushort4 v0 = *((const ushort4*)(h + (size_t)s0 * OUT_F) + lane);
        const ushort4 v1 = *((const ushort4*)(h + (size_t)s1 * OUT_F) + lane);
        a0 += bf2f(v0.x); a1 += bf2f(v0.y); a2 += bf2f(v0.z); a3 += bf2f(v0.w);
        a0 += bf2f(v1.x); a1 += bf2f(v1.y); a2 += bf2f(v1.z); a3 += bf2f(v1.w);
    }
    if (j < end) {
        const int s0 = csr_src[j];
        const ushort4 v0 = *((const ushort4*)(h + (size_t)s0 * OUT_F) + lane);
        a0 += bf2f(v0.x); a1 += bf2f(v0.y); a2 += bf2f(v0.z); a3 += bf2f(v0.w);
    }
    f32x4 o; o[0] = a0; o[1] = a1; o[2] = a2; o[3] = a3;
    *((f32x4*)(out + (size_t)n * OUT_F) + lane) = o;
}

// ---------------- fallback atomic scatter (small ws) ----------------
__global__ __launch_bounds__(256) void gcn_scatter_kernel(
    const uint16_t* __restrict__ h, const int* __restrict__ src,
    const int* __restrict__ dst, float* __restrict__ out)
{
    const int e = (blockIdx.x << 2) | (threadIdx.x >> 6);
    if (e >= N_EDGES) return;
    const int lane = threadIdx.x & 63;
    const int s = src[e];
    const int d = dst[e];
    const ushort4 v = *((const ushort4*)(h + (size_t)s * OUT_F) + lane);
    float* op = out + (size_t)d * OUT_F + (lane << 2);
    unsafeAtomicAdd(op + 0, bf2f(v.x));
    unsafeAtomicAdd(op + 1, bf2f(v.y));
    unsafeAtomicAdd(op + 2, bf2f(v.z));
    unsafeAtomicAdd(op + 3, bf2f(v.w));
}

static inline size_t align256(size_t x) { return (x + 255) & ~(size_t)255; }

extern "C" void kernel_launch(void* const* d_in, const int* in_sizes, int n_in,
                              void* d_out, int out_size, void* d_ws, size_t ws_size,
                              hipStream_t stream) {
    const float* feat = (const float*)d_in[0];
    const float* W    = (const float*)d_in[1];
    const float* bias = (const float*)d_in[2];
    const int*   src  = (const int*)d_in[3];
    const int*   dst  = (const int*)d_in[4];
    float*       out  = (float*)d_out;

    char* ws = (char*)d_ws;
    size_t off = 0;
    uint16_t* h      = (uint16_t*)(ws + off);   off = align256(off + (size_t)N_NODES * OUT_F * 2);
    uint16_t* w_frag = (uint16_t*)(ws + off);   off = align256(off + (size_t)OUT_F * IN_F * 2);
    int* deg      = (int*)(ws + off);           off = align256(off + (size_t)N_NODES * 4);
    int* start    = (int*)(ws + off);           off = align256(off + (size_t)N_NODES * 4);
    int* cursor   = (int*)(ws + off);           off = align256(off + (size_t)N_NODES * 4);
    int* chunkSum = (int*)(ws + off);           off = align256(off + (size_t)NCHUNKS * 4);
    int* chunkOff = (int*)(ws + off);           off = align256(off + (size_t)NCHUNKS * 4);
    int* csr_src  = (int*)(ws + off);           off = align256(off + (size_t)N_EDGES * 4);
    const bool csr_ok = (off <= ws_size);

    const int mtiles = (N_NODES + BM - 1) / BM;  // 782

    w_frag_kernel<<<64, 256, 0, stream>>>(W, w_frag);
    gcn_gemm_kernel<<<mtiles * 2, 256, 0, stream>>>(feat, w_frag, bias, h);

    if (csr_ok) {
        hipMemsetAsync(deg, 0, (size_t)N_NODES * 4, stream);
        const int eblocks = (N_EDGES + 255) / 256;  // 6250
        hist_kernel<<<eblocks, 256, 0, stream>>>(dst, deg);
        chunk_reduce_kernel<<<NCHUNKS, 256, 0, stream>>>(deg, chunkSum);
        scan_chunksums_kernel<<<1, 64, 0, stream>>>(chunkSum, chunkOff);
        chunk_scan_kernel<<<NCHUNKS, 256, 0, stream>>>(deg, chunkOff, start, cursor);
        csr_fill_kernel<<<eblocks, 256, 0, stream>>>(src, dst, cursor, csr_src);
        gcn_gather_kernel<<<(N_NODES + 3) / 4, 256, 0, stream>>>(h, start, csr_src, out);
    } else {
        hipMemsetAsync(out, 0, (size_t)out_size * sizeof(float), stream);
        gcn_scatter_kernel<<<(N_EDGES + 3) / 4, 256, 0, stream>>>(h, src, dst, out);
    }
}

// Round 6
// 445.148 us; speedup vs baseline: 1.1232x; 1.1232x over previous
//
#include <hip/hip_runtime.h>
#include <hip/hip_bf16.h>
#include <stdint.h>

#define N_NODES 100000
#define IN_F    512
#define OUT_F   256
#define N_EDGES 1600000

typedef __attribute__((ext_vector_type(4))) float f32x4;
typedef __attribute__((ext_vector_type(8))) short bf16x8;
typedef __attribute__((ext_vector_type(4))) uint32_t u32x4;

#define BM 128
#define BK 32
#define KT_TILES (IN_F / BK)             // 16
#define LDW (BK + 8)                     // 80 B row stride
#define WFRAG_KT_STRIDE (16 * 16 * 32)   // 8192 elems per kt slab

#define SCAN_CHUNK 4096
#define NCHUNKS ((N_NODES + SCAN_CHUNK - 1) / SCAN_CHUNK)   // 25

__device__ __forceinline__ float bf2f(uint16_t u) {
    union { uint32_t i; float f; } c; c.i = ((uint32_t)u) << 16; return c.f;
}
__device__ __forceinline__ uint16_t f2bf(float f) {
    union { float f; uint32_t i; } c; c.f = f;
    uint32_t x = c.i;
    return (uint16_t)((x + 0x7FFFu + ((x >> 16) & 1u)) >> 16);  // RNE
}
__device__ __forceinline__ uint32_t cvt_pk_bf16(float a, float b) {
    uint32_t r;
    asm("v_cvt_pk_bf16_f32 %0, %1, %2" : "=v"(r) : "v"(a), "v"(b));
    return r;
}

// ---------------- W -> bf16 fragment-order ----------------
// w_frag[((kt*16 + cg)*16 + lrow)*32 + kg*8 + j] = bf16(W[cg*16+lrow][kt*32+kg*8+j])
__global__ __launch_bounds__(256) void w_frag_kernel(
    const float* __restrict__ W, uint16_t* __restrict__ w_frag)
{
    const int gid = blockIdx.x * 256 + threadIdx.x;   // 16384 groups of 8 elems
    if (gid >= 16384) return;
    const int kg = gid & 3, lrow = (gid >> 2) & 15, cg = (gid >> 6) & 15, kt = gid >> 10;
    const float* s = W + (size_t)(cg * 16 + lrow) * IN_F + kt * 32 + kg * 8;
    const f32x4 v0 = *(const f32x4*)s;
    const f32x4 v1 = *(const f32x4*)(s + 4);
    u32x4 c;
    c[0] = cvt_pk_bf16(v0[0], v0[1]);
    c[1] = cvt_pk_bf16(v0[2], v0[3]);
    c[2] = cvt_pk_bf16(v1[0], v1[1]);
    c[3] = cvt_pk_bf16(v1[2], v1[3]);
    *(u32x4*)(w_frag + (size_t)gid * 8) = c;
}

// ---------------- GEMM: h = bf16(feat @ W^T + b) ----------------
// 512 threads / 8 waves (2x4). BM=128, BN=256 (full N in one block -> A staged
// once). A: LDS double-buffered bf16, register prefetch 2 tiles ahead, one
// barrier per kt. B: per-iter fragment loads from L2-resident w_frag.
__global__ __launch_bounds__(512) void gcn_gemm_kernel(
    const float* __restrict__ feat, const uint16_t* __restrict__ w_frag,
    const float* __restrict__ bias, uint16_t* __restrict__ h)
{
    __shared__ uint16_t At[2][BM][LDW];   // 20.5 KB

    const int m0 = blockIdx.x * BM;

    const int t    = threadIdx.x;
    const int wid  = t >> 6;
    const int lane = t & 63;
    const int wr   = wid >> 2, wc = wid & 3;   // 2x4 waves, 64x64 tile per wave
    const int lrow = lane & 15;
    const int kg   = lane >> 4;

    const int srow = t >> 2;     // staging row 0..127
    const int sq   = t & 3;      // 8-float quarter of the 32-float row chunk
    const bool arow_ok = (m0 + srow) < N_NODES;
    const float* gA = feat + (size_t)(m0 + srow) * IN_F + sq * 8;
    const f32x4 zero = {0.f, 0.f, 0.f, 0.f};

    f32x4 acc[4][4] = {};

    // B fragment pointers (cols wc*64 + n*16)
    const uint16_t* wfp[4];
    #pragma unroll
    for (int n = 0; n < 4; ++n) {
        const int cg = wc * 4 + n;
        wfp[n] = w_frag + ((size_t)cg * 16 + lrow) * 32 + kg * 8;
    }

    // staging register double-buffer (2 tiles in flight, 8 floats each)
    f32x4 sE[2], sO[2];

#define STAGE_LOAD(SV, KT)                                                \
    do {                                                                  \
        const f32x4* p_ = (const f32x4*)(gA + (KT) * BK);                 \
        SV[0] = arow_ok ? p_[0] : zero;                                   \
        SV[1] = arow_ok ? p_[1] : zero;                                   \
    } while (0)

#define STAGE_WRITE(SV, BUF)                                              \
    do {                                                                  \
        u32x4 c_;                                                         \
        c_[0] = cvt_pk_bf16(SV[0][0], SV[0][1]);                          \
        c_[1] = cvt_pk_bf16(SV[0][2], SV[0][3]);                          \
        c_[2] = cvt_pk_bf16(SV[1][0], SV[1][1]);                          \
        c_[3] = cvt_pk_bf16(SV[1][2], SV[1][3]);                          \
        *(u32x4*)&At[BUF][srow][sq * 8] = c_;                             \
    } while (0)

    // prologue: tile0 staged, tile1 in flight
    STAGE_LOAD(sE, 0);
    STAGE_WRITE(sE, 0);
    STAGE_LOAD(sE, 1);   // tile1 -> writes buf1 at kt=0
    STAGE_LOAD(sO, 2);   // tile2 -> writes buf0 at kt=1
    __syncthreads();

    #pragma unroll
    for (int kt = 0; kt < KT_TILES; ++kt) {
        // A fragments from current buffer
        bf16x8 af[4];
        #pragma unroll
        for (int m = 0; m < 4; ++m)
            af[m] = *(const bf16x8*)&At[kt & 1][wr * 64 + m * 16 + lrow][kg * 8];
        // B fragments (L2-resident)
        bf16x8 bf[4];
        #pragma unroll
        for (int n = 0; n < 4; ++n)
            bf[n] = *(const bf16x8*)(wfp[n] + (size_t)kt * WFRAG_KT_STRIDE);
        #pragma unroll
        for (int m = 0; m < 4; ++m)
            #pragma unroll
            for (int n = 0; n < 4; ++n)
                acc[m][n] = __builtin_amdgcn_mfma_f32_16x16x32_bf16(
                    af[m], bf[n], acc[m][n], 0, 0, 0);
        // stage tile kt+1 into the other buffer; issue loads for kt+3
        if (kt + 1 < KT_TILES) {
            if (kt & 1) {
                STAGE_WRITE(sO, (kt + 1) & 1);
                if (kt + 3 < KT_TILES) STAGE_LOAD(sO, kt + 3);
            } else {
                STAGE_WRITE(sE, (kt + 1) & 1);
                if (kt + 3 < KT_TILES) STAGE_LOAD(sE, kt + 3);
            }
            __syncthreads();
        }
    }
#undef STAGE_LOAD
#undef STAGE_WRITE

    // ---- epilogue: bias + bf16 store ----
    #pragma unroll
    for (int n = 0; n < 4; ++n) {
        const int col = wc * 64 + n * 16 + lrow;
        const float bv = bias[col];
        #pragma unroll
        for (int m = 0; m < 4; ++m) {
            #pragma unroll
            for (int j = 0; j < 4; ++j) {
                const int row = m0 + wr * 64 + m * 16 + kg * 4 + j;
                if (row < N_NODES)
                    h[(size_t)row * OUT_F + col] = f2bf(acc[m][n][j] + bv);
            }
        }
    }
}

// ---------------- CSR build ----------------
__global__ __launch_bounds__(256) void hist_kernel(
    const int* __restrict__ dst, int* __restrict__ deg)
{
    const int e = blockIdx.x * 256 + threadIdx.x;
    if (e < N_EDGES) atomicAdd(&deg[dst[e]], 1);
}

__global__ __launch_bounds__(256) void chunk_reduce_kernel(
    const int* __restrict__ deg, int* __restrict__ chunkSum)
{
    __shared__ int red[256];
    const int b = blockIdx.x, t = threadIdx.x;
    const int base = b * SCAN_CHUNK;
    int s = 0;
    #pragma unroll
    for (int i = 0; i < 16; ++i) {
        const int idx = base + t * 16 + i;
        s += (idx < N_NODES) ? deg[idx] : 0;
    }
    red[t] = s;
    __syncthreads();
    for (int off = 128; off > 0; off >>= 1) {
        if (t < off) red[t] += red[t + off];
        __syncthreads();
    }
    if (t == 0) chunkSum[b] = red[0];
}

__global__ void scan_chunksums_kernel(const int* __restrict__ chunkSum,
                                      int* __restrict__ chunkOff)
{
    if (threadIdx.x == 0 && blockIdx.x == 0) {
        int acc = 0;
        for (int i = 0; i < NCHUNKS; ++i) { chunkOff[i] = acc; acc += chunkSum[i]; }
    }
}

__global__ __launch_bounds__(256) void chunk_scan_kernel(
    const int* __restrict__ deg, const int* __restrict__ chunkOff,
    int* __restrict__ start, int* __restrict__ cursor)
{
    __shared__ int tsum[256];
    const int b = blockIdx.x, t = threadIdx.x;
    const int base = b * SCAN_CHUNK;
    int vals[16];
    int s = 0;
    #pragma unroll
    for (int i = 0; i < 16; ++i) {
        const int idx = base + t * 16 + i;
        const int v = (idx < N_NODES) ? deg[idx] : 0;
        vals[i] = s;
        s += v;
    }
    int x = s;
    tsum[t] = x;
    __syncthreads();
    #pragma unroll
    for (int off = 1; off < 256; off <<= 1) {
        const int y = (t >= off) ? tsum[t - off] : 0;
        __syncthreads();
        x += y;
        tsum[t] = x;
        __syncthreads();
    }
    const int thread_off = chunkOff[b] + (t == 0 ? 0 : tsum[t - 1]);
    #pragma unroll
    for (int i = 0; i < 16; ++i) {
        const int idx = base + t * 16 + i;
        if (idx < N_NODES) {
            const int st = thread_off + vals[i];
            start[idx] = st;
            cursor[idx] = st;
        }
    }
}

__global__ __launch_bounds__(256) void csr_fill_kernel(
    const int* __restrict__ src, const int* __restrict__ dst,
    int* __restrict__ cursor, int* __restrict__ csr_src)
{
    const int e = blockIdx.x * 256 + threadIdx.x;
    if (e < N_EDGES) {
        const int d = dst[e];
        const int p = atomicAdd(&cursor[d], 1);
        csr_src[p] = src[e];
    }
}

// ---------------- gather: one wave per dst node, atomic-free ----------------
__global__ __launch_bounds__(256) void gcn_gather_kernel(
    const uint16_t* __restrict__ h, const int* __restrict__ start,
    const int* __restrict__ csr_src, float* __restrict__ out)
{
    const int n = blockIdx.x * 4 + (threadIdx.x >> 6);
    if (n >= N_NODES) return;
    const int lane = threadIdx.x & 63;
    const int beg = start[n];
    const int end = (n == N_NODES - 1) ? N_EDGES : start[n + 1];

    float a0 = 0.f, a1 = 0.f, a2 = 0.f, a3 = 0.f;
    int j = beg;
    for (; j + 3 < end; j += 4) {
        const int s0 = csr_src[j];
        const int s1 = csr_src[j + 1];
        const int s2 = csr_src[j + 2];
        const int s3 = csr_src[j + 3];
        const ushort4 v0 = *((const ushort4*)(h + (size_t)s0 * OUT_F) + lane);
        const ushort4 v1 = *((const ushort4*)(h + (size_t)s1 * OUT_F) + lane);
        const ushort4 v2 = *((const ushort4*)(h + (size_t)s2 * OUT_F) + lane);
        const ushort4 v3 = *((const ushort4*)(h + (size_t)s3 * OUT_F) + lane);
        a0 += bf2f(v0.x); a1 += bf2f(v0.y); a2 += bf2f(v0.z); a3 += bf2f(v0.w);
        a0 += bf2f(v1.x); a1 += bf2f(v1.y); a2 += bf2f(v1.z); a3 += bf2f(v1.w);
        a0 += bf2f(v2.x); a1 += bf2f(v2.y); a2 += bf2f(v2.z); a3 += bf2f(v2.w);
        a0 += bf2f(v3.x); a1 += bf2f(v3.y); a2 += bf2f(v3.z); a3 += bf2f(v3.w);
    }
    for (; j < end; ++j) {
        const int s0 = csr_src[j];
        const ushort4 v0 = *((const ushort4*)(h + (size_t)s0 * OUT_F) + lane);
        a0 += bf2f(v0.x); a1 += bf2f(v0.y); a2 += bf2f(v0.z); a3 += bf2f(v0.w);
    }
    f32x4 o; o[0] = a0; o[1] = a1; o[2] = a2; o[3] = a3;
    *((f32x4*)(out + (size_t)n * OUT_F) + lane) = o;
}

// ---------------- fallback atomic scatter (small ws) ----------------
__global__ __launch_bounds__(256) void gcn_scatter_kernel(
    const uint16_t* __restrict__ h, const int* __restrict__ src,
    const int* __restrict__ dst, float* __restrict__ out)
{
    const int e = (blockIdx.x << 2) | (threadIdx.x >> 6);
    if (e >= N_EDGES) return;
    const int lane = threadIdx.x & 63;
    const int s = src[e];
    const int d = dst[e];
    const ushort4 v = *((const ushort4*)(h + (size_t)s * OUT_F) + lane);
    float* op = out + (size_t)d * OUT_F + (lane << 2);
    unsafeAtomicAdd(op + 0, bf2f(v.x));
    unsafeAtomicAdd(op + 1, bf2f(v.y));
    unsafeAtomicAdd(op + 2, bf2f(v.z));
    unsafeAtomicAdd(op + 3, bf2f(v.w));
}

static inline size_t align256(size_t x) { return (x + 255) & ~(size_t)255; }

extern "C" void kernel_launch(void* const* d_in, const int* in_sizes, int n_in,
                              void* d_out, int out_size, void* d_ws, size_t ws_size,
                              hipStream_t stream) {
    const float* feat = (const float*)d_in[0];
    const float* W    = (const float*)d_in[1];
    const float* bias = (const float*)d_in[2];
    const int*   src  = (const int*)d_in[3];
    const int*   dst  = (const int*)d_in[4];
    float*       out  = (float*)d_out;

    char* ws = (char*)d_ws;
    size_t off = 0;
    uint16_t* h      = (uint16_t*)(ws + off);   off = align256(off + (size_t)N_NODES * OUT_F * 2);
    uint16_t* w_frag = (uint16_t*)(ws + off);   off = align256(off + (size_t)OUT_F * IN_F * 2);
    int* deg      = (int*)(ws + off);           off = align256(off + (size_t)N_NODES * 4);
    int* start    = (int*)(ws + off);           off = align256(off + (size_t)N_NODES * 4);
    int* cursor   = (int*)(ws + off);           off = align256(off + (size_t)N_NODES * 4);
    int* chunkSum = (int*)(ws + off);           off = align256(off + (size_t)NCHUNKS * 4);
    int* chunkOff = (int*)(ws + off);           off = align256(off + (size_t)NCHUNKS * 4);
    int* csr_src  = (int*)(ws + off);           off = align256(off + (size_t)N_EDGES * 4);
    const bool csr_ok = (off <= ws_size);

    const int mtiles = (N_NODES + BM - 1) / BM;  // 782

    w_frag_kernel<<<64, 256, 0, stream>>>(W, w_frag);
    gcn_gemm_kernel<<<mtiles, 512, 0, stream>>>(feat, w_frag, bias, h);

    if (csr_ok) {
        hipMemsetAsync(deg, 0, (size_t)N_NODES * 4, stream);
        const int eblocks = (N_EDGES + 255) / 256;  // 6250
        hist_kernel<<<eblocks, 256, 0, stream>>>(dst, deg);
        chunk_reduce_kernel<<<NCHUNKS, 256, 0, stream>>>(deg, chunkSum);
        scan_chunksums_kernel<<<1, 64, 0, stream>>>(chunkSum, chunkOff);
        chunk_scan_kernel<<<NCHUNKS, 256, 0, stream>>>(deg, chunkOff, start, cursor);
        csr_fill_kernel<<<eblocks, 256, 0, stream>>>(src, dst, cursor, csr_src);
        gcn_gather_kernel<<<(N_NODES + 3) / 4, 256, 0, stream>>>(h, start, csr_src, out);
    } else {
        hipMemsetAsync(out, 0, (size_t)out_size * sizeof(float), stream);
        gcn_scatter_kernel<<<(N_EDGES + 3) / 4, 256, 0, stream>>>(h, src, dst, out);
    }
}

// Round 7
// 395.462 us; speedup vs baseline: 1.2643x; 1.1256x over previous
//
#include <hip/hip_runtime.h>
#include <hip/hip_bf16.h>
#include <stdint.h>

#define N_NODES 100000
#define IN_F    512
#define OUT_F   256
#define N_EDGES 1600000

typedef __attribute__((ext_vector_type(4))) float f32x4;
typedef __attribute__((ext_vector_type(8))) short bf16x8;
typedef __attribute__((ext_vector_type(4))) uint32_t u32x4;

#define BM 128
#define BK 32
#define KT_TILES (IN_F / BK)             // 16
#define WFRAG_KT_STRIDE (16 * 16 * 32)   // 8192 elems per kt slab
#define EPS 66                            // epilogue LDS row stride (bf16)

#define SCAN_CHUNK 4096
#define NCHUNKS ((N_NODES + SCAN_CHUNK - 1) / SCAN_CHUNK)   // 25

__device__ __forceinline__ float bf2f(uint16_t u) {
    union { uint32_t i; float f; } c; c.i = ((uint32_t)u) << 16; return c.f;
}
__device__ __forceinline__ uint16_t f2bf(float f) {
    union { float f; uint32_t i; } c; c.f = f;
    uint32_t x = c.i;
    return (uint16_t)((x + 0x7FFFu + ((x >> 16) & 1u)) >> 16);  // RNE
}
__device__ __forceinline__ uint32_t cvt_pk_bf16(float a, float b) {
    uint32_t r;
    asm("v_cvt_pk_bf16_f32 %0, %1, %2" : "=v"(r) : "v"(a), "v"(b));
    return r;
}
// async global->LDS, 16B per lane; LDS dest = wave-uniform base + lane*16
__device__ __forceinline__ void gload_lds16(const float* g, float* l) {
    __builtin_amdgcn_global_load_lds(
        (const __attribute__((address_space(1))) void*)g,
        (__attribute__((address_space(3))) void*)l, 16, 0, 0);
}

// ---------------- W -> bf16 fragment-order ----------------
// w_frag[((kt*16 + cg)*16 + lrow)*32 + kg*8 + j] = bf16(W[cg*16+lrow][kt*32+kg*8+j])
__global__ __launch_bounds__(256) void w_frag_kernel(
    const float* __restrict__ W, uint16_t* __restrict__ w_frag)
{
    const int gid = blockIdx.x * 256 + threadIdx.x;   // 16384 groups of 8 elems
    if (gid >= 16384) return;
    const int kg = gid & 3, lrow = (gid >> 2) & 15, cg = (gid >> 6) & 15, kt = gid >> 10;
    const float* s = W + (size_t)(cg * 16 + lrow) * IN_F + kt * 32 + kg * 8;
    const f32x4 v0 = *(const f32x4*)s;
    const f32x4 v1 = *(const f32x4*)(s + 4);
    u32x4 c;
    c[0] = cvt_pk_bf16(v0[0], v0[1]);
    c[1] = cvt_pk_bf16(v0[2], v0[3]);
    c[2] = cvt_pk_bf16(v1[0], v1[1]);
    c[3] = cvt_pk_bf16(v1[2], v1[3]);
    *(u32x4*)(w_frag + (size_t)gid * 8) = c;
}

// ---------------- GEMM: h = bf16(feat @ W^T + b) ----------------
// 512 thr / 8 waves (2x4), BM=128 x BN=256. A: fp32 staged by global_load_lds
// (width 16) into linear double-buffered LDS with XOR-chunk swizzle applied on
// the GLOBAL source and the LDS READ (both-sides rule). Convert fp32->bf16 at
// fragment read via v_cvt_pk_bf16_f32. B: bf16 fragments from L2-resident
// w_frag, register double-buffered. One barrier per kt. Epilogue transposes
// each wave's 64x64 tile through LDS for coalesced 8B stores of h.
__global__ __launch_bounds__(512) void gcn_gemm_kernel(
    const float* __restrict__ feat, const uint16_t* __restrict__ w_frag,
    const float* __restrict__ bias, uint16_t* __restrict__ h)
{
    __shared__ __align__(16) char smem_raw[2 * BM * BK * 4];   // 32 KB
    float (*At)[BM][BK] = (float (*)[BM][BK])smem_raw;

    const int m0 = blockIdx.x * BM;

    const int t    = threadIdx.x;
    const int wid  = t >> 6;
    const int lane = t & 63;
    const int wr   = wid >> 2, wc = wid & 3;   // 2x4 waves, 64x64 tile per wave
    const int lrow = lane & 15;
    const int kg   = lane >> 4;

    f32x4 acc[4][4] = {};

    // ---- staging geometry: wave wid stages rows wid*16 .. wid*16+15 ----
    // instr i (0,1) covers rows wid*16+i*8 .. +7; lane -> row +(lane>>3), chunk lane&7.
    const int r8 = lane >> 3;          // row&7 for staged row (bases are mult of 8)
    const int sp = lane & 7;           // physical 16B chunk within row
    const int sc = sp ^ r8;            // logical chunk fetched (swizzle)
    const float* gsrc[2];
    #pragma unroll
    for (int i = 0; i < 2; ++i) {
        int grow = m0 + wid * 16 + i * 8 + r8;
        if (grow > N_NODES - 1) grow = N_NODES - 1;   // clamp: garbage rows masked at store
        gsrc[i] = feat + (size_t)grow * IN_F + sc * 4;
    }

#define STAGE(KT, BUF)                                                     \
    do {                                                                   \
        gload_lds16(gsrc[0] + (KT) * BK, &At[BUF][wid * 16][0]);           \
        gload_lds16(gsrc[1] + (KT) * BK, &At[BUF][wid * 16 + 8][0]);       \
    } while (0)

    // ---- B fragment pointers ----
    const uint16_t* wfp[4];
    #pragma unroll
    for (int n = 0; n < 4; ++n) {
        const int cg = wc * 4 + n;
        wfp[n] = w_frag + ((size_t)cg * 16 + lrow) * 32 + kg * 8;
    }

    bf16x8 bfr[2][4];

    // ---- prologue ----
    STAGE(0, 0);
    #pragma unroll
    for (int n = 0; n < 4; ++n) bfr[0][n] = *(const bf16x8*)(wfp[n]);
    __syncthreads();   // drains stage 0

    // read-side swizzle: row&7 == lrow&7 for every fragment row
    const int p0 = (2 * kg) ^ (lrow & 7);
    const int p1 = p0 ^ 1;

    #pragma unroll
    for (int kt = 0; kt < KT_TILES; ++kt) {
        const int cur = kt & 1, nxt = cur ^ 1;
        if (kt + 1 < KT_TILES) {
            STAGE(kt + 1, nxt);
            #pragma unroll
            for (int n = 0; n < 4; ++n)
                bfr[nxt][n] = *(const bf16x8*)(wfp[n] + (size_t)(kt + 1) * WFRAG_KT_STRIDE);
        }
        bf16x8 af[4];
        #pragma unroll
        for (int m = 0; m < 4; ++m) {
            const int row = wr * 64 + m * 16 + lrow;
            const f32x4 v0 = *(const f32x4*)&At[cur][row][p0 * 4];  // floats kg*8..+3
            const f32x4 v1 = *(const f32x4*)&At[cur][row][p1 * 4];  // floats kg*8+4..+7
            union { bf16x8 v; uint32_t u[4]; } c_;
            c_.u[0] = cvt_pk_bf16(v0[0], v0[1]);
            c_.u[1] = cvt_pk_bf16(v0[2], v0[3]);
            c_.u[2] = cvt_pk_bf16(v1[0], v1[1]);
            c_.u[3] = cvt_pk_bf16(v1[2], v1[3]);
            af[m] = c_.v;
        }
        #pragma unroll
        for (int m = 0; m < 4; ++m)
            #pragma unroll
            for (int n = 0; n < 4; ++n)
                acc[m][n] = __builtin_amdgcn_mfma_f32_16x16x32_bf16(
                    af[m], bfr[cur][n], acc[m][n], 0, 0, 0);
        if (kt + 1 < KT_TILES) __syncthreads();   // reads done + nxt stage drained
    }
#undef STAGE

    __syncthreads();   // LDS reuse for epilogue

    // ---- epilogue: per-wave 64x64 transpose through LDS, coalesced stores ----
    uint16_t* ep = (uint16_t*)smem_raw;
    const int wbase = wid * (16 * EPS);   // 1056 elems/wave
    float bv[4];
    #pragma unroll
    for (int n = 0; n < 4; ++n) bv[n] = bias[wc * 64 + n * 16 + lrow];

    #pragma unroll
    for (int m = 0; m < 4; ++m) {
        #pragma unroll
        for (int n = 0; n < 4; ++n)
            #pragma unroll
            for (int j = 0; j < 4; ++j)
                ep[wbase + (kg * 4 + j) * EPS + n * 16 + lrow] = f2bf(acc[m][n][j] + bv[n]);
        __syncthreads();
        #pragma unroll
        for (int g = 0; g < 4; ++g) {
            const int r16  = g * 4 + (lane >> 4);      // 0..15
            const int cidx = (lane & 15) * 4;          // 4 bf16 = 8B per lane
            const int ib = wbase + r16 * EPS + cidx;   // even -> 4B aligned
            uint2 v;
            v.x = *(const uint32_t*)&ep[ib];
            v.y = *(const uint32_t*)&ep[ib + 2];
            const int row = m0 + wr * 64 + m * 16 + r16;
            if (row < N_NODES)
                *(uint2*)(h + (size_t)row * OUT_F + wc * 64 + cidx) = v;
        }
        __syncthreads();
    }
}

// ---------------- CSR build ----------------
__global__ __launch_bounds__(256) void hist_kernel(
    const int* __restrict__ dst, int* __restrict__ deg)
{
    const int e = blockIdx.x * 256 + threadIdx.x;
    if (e < N_EDGES) atomicAdd(&deg[dst[e]], 1);
}

__global__ __launch_bounds__(256) void chunk_reduce_kernel(
    const int* __restrict__ deg, int* __restrict__ chunkSum)
{
    __shared__ int red[256];
    const int b = blockIdx.x, t = threadIdx.x;
    const int base = b * SCAN_CHUNK;
    int s = 0;
    #pragma unroll
    for (int i = 0; i < 16; ++i) {
        const int idx = base + t * 16 + i;
        s += (idx < N_NODES) ? deg[idx] : 0;
    }
    red[t] = s;
    __syncthreads();
    for (int off = 128; off > 0; off >>= 1) {
        if (t < off) red[t] += red[t + off];
        __syncthreads();
    }
    if (t == 0) chunkSum[b] = red[0];
}

__global__ void scan_chunksums_kernel(const int* __restrict__ chunkSum,
                                      int* __restrict__ chunkOff)
{
    if (threadIdx.x == 0 && blockIdx.x == 0) {
        int acc = 0;
        for (int i = 0; i < NCHUNKS; ++i) { chunkOff[i] = acc; acc += chunkSum[i]; }
    }
}

__global__ __launch_bounds__(256) void chunk_scan_kernel(
    const int* __restrict__ deg, const int* __restrict__ chunkOff,
    int* __restrict__ start, int* __restrict__ cursor)
{
    __shared__ int tsum[256];
    const int b = blockIdx.x, t = threadIdx.x;
    const int base = b * SCAN_CHUNK;
    int vals[16];
    int s = 0;
    #pragma unroll
    for (int i = 0; i < 16; ++i) {
        const int idx = base + t * 16 + i;
        const int v = (idx < N_NODES) ? deg[idx] : 0;
        vals[i] = s;
        s += v;
    }
    int x = s;
    tsum[t] = x;
    __syncthreads();
    #pragma unroll
    for (int off = 1; off < 256; off <<= 1) {
        const int y = (t >= off) ? tsum[t - off] : 0;
        __syncthreads();
        x += y;
        tsum[t] = x;
        __syncthreads();
    }
    const int thread_off = chunkOff[b] + (t == 0 ? 0 : tsum[t - 1]);
    #pragma unroll
    for (int i = 0; i < 16; ++i) {
        const int idx = base + t * 16 + i;
        if (idx < N_NODES) {
            const int st = thread_off + vals[i];
            start[idx] = st;
            cursor[idx] = st;
        }
    }
}

__global__ __launch_bounds__(256) void csr_fill_kernel(
    const int* __restrict__ src, const int* __restrict__ dst,
    int* __restrict__ cursor, int* __restrict__ csr_src)
{
    const int e = blockIdx.x * 256 + threadIdx.x;
    if (e < N_EDGES) {
        const int d = dst[e];
        const int p = atomicAdd(&cursor[d], 1);
        csr_src[p] = src[e];
    }
}

// ---------------- gather: one wave per dst node, atomic-free ----------------
__global__ __launch_bounds__(256) void gcn_gather_kernel(
    const uint16_t* __restrict__ h, const int* __restrict__ start,
    const int* __restrict__ csr_src, float* __restrict__ out)
{
    const int n = blockIdx.x * 4 + (threadIdx.x >> 6);
    if (n >= N_NODES) return;
    const int lane = threadIdx.x & 63;
    const int beg = start[n];
    const int end = (n == N_NODES - 1) ? N_EDGES : start[n + 1];

    float a0 = 0.f, a1 = 0.f, a2 = 0.f, a3 = 0.f;
    int j = beg;
    for (; j + 3 < end; j += 4) {
        const int s0 = csr_src[j];
        const int s1 = csr_src[j + 1];
        const int s2 = csr_src[j + 2];
        const int s3 = csr_src[j + 3];
        const ushort4 v0 = *((const ushort4*)(h + (size_t)s0 * OUT_F) + lane);
        const ushort4 v1 = *((const ushort4*)(h + (size_t)s1 * OUT_F) + lane);
        const ushort4 v2 = *((const ushort4*)(h + (size_t)s2 * OUT_F) + lane);
        const ushort4 v3 = *((const ushort4*)(h + (size_t)s3 * OUT_F) + lane);
        a0 += bf2f(v0.x); a1 += bf2f(v0.y); a2 += bf2f(v0.z); a3 += bf2f(v0.w);
        a0 += bf2f(v1.x); a1 += bf2f(v1.y); a2 += bf2f(v1.z); a3 += bf2f(v1.w);
        a0 += bf2f(v2.x); a1 += bf2f(v2.y); a2 += bf2f(v2.z); a3 += bf2f(v2.w);
        a0 += bf2f(v3.x); a1 += bf2f(v3.y); a2 += bf2f(v3.z); a3 += bf2f(v3.w);
    }
    for (; j < end; ++j) {
        const int s0 = csr_src[j];
        const ushort4 v0 = *((const ushort4*)(h + (size_t)s0 * OUT_F) + lane);
        a0 += bf2f(v0.x); a1 += bf2f(v0.y); a2 += bf2f(v0.z); a3 += bf2f(v0.w);
    }
    f32x4 o; o[0] = a0; o[1] = a1; o[2] = a2; o[3] = a3;
    *((f32x4*)(out + (size_t)n * OUT_F) + lane) = o;
}

// ---------------- fallback atomic scatter (small ws) ----------------
__global__ __launch_bounds__(256) void gcn_scatter_kernel(
    const uint16_t* __restrict__ h, const int* __restrict__ src,
    const int* __restrict__ dst, float* __restrict__ out)
{
    const int e = (blockIdx.x << 2) | (threadIdx.x >> 6);
    if (e >= N_EDGES) return;
    const int lane = threadIdx.x & 63;
    const int s = src[e];
    const int d = dst[e];
    const ushort4 v = *((const ushort4*)(h + (size_t)s * OUT_F) + lane);
    float* op = out + (size_t)d * OUT_F + (lane << 2);
    unsafeAtomicAdd(op + 0, bf2f(v.x));
    unsafeAtomicAdd(op + 1, bf2f(v.y));
    unsafeAtomicAdd(op + 2, bf2f(v.z));
    unsafeAtomicAdd(op + 3, bf2f(v.w));
}

static inline size_t align256(size_t x) { return (x + 255) & ~(size_t)255; }

extern "C" void kernel_launch(void* const* d_in, const int* in_sizes, int n_in,
                              void* d_out, int out_size, void* d_ws, size_t ws_size,
                              hipStream_t stream) {
    const float* feat = (const float*)d_in[0];
    const float* W    = (const float*)d_in[1];
    const float* bias = (const float*)d_in[2];
    const int*   src  = (const int*)d_in[3];
    const int*   dst  = (const int*)d_in[4];
    float*       out  = (float*)d_out;

    char* ws = (char*)d_ws;
    size_t off = 0;
    uint16_t* h      = (uint16_t*)(ws + off);   off = align256(off + (size_t)N_NODES * OUT_F * 2);
    uint16_t* w_frag = (uint16_t*)(ws + off);   off = align256(off + (size_t)OUT_F * IN_F * 2);
    int* deg      = (int*)(ws + off);           off = align256(off + (size_t)N_NODES * 4);
    int* start    = (int*)(ws + off);           off = align256(off + (size_t)N_NODES * 4);
    int* cursor   = (int*)(ws + off);           off = align256(off + (size_t)N_NODES * 4);
    int* chunkSum = (int*)(ws + off);           off = align256(off + (size_t)NCHUNKS * 4);
    int* chunkOff = (int*)(ws + off);           off = align256(off + (size_t)NCHUNKS * 4);
    int* csr_src  = (int*)(ws + off);           off = align256(off + (size_t)N_EDGES * 4);
    const bool csr_ok = (off <= ws_size);

    const int mtiles = (N_NODES + BM - 1) / BM;  // 782

    w_frag_kernel<<<64, 256, 0, stream>>>(W, w_frag);
    gcn_gemm_kernel<<<mtiles, 512, 0, stream>>>(feat, w_frag, bias, h);

    if (csr_ok) {
        hipMemsetAsync(deg, 0, (size_t)N_NODES * 4, stream);
        const int eblocks = (N_EDGES + 255) / 256;  // 6250
        hist_kernel<<<eblocks, 256, 0, stream>>>(dst, deg);
        chunk_reduce_kernel<<<NCHUNKS, 256, 0, stream>>>(deg, chunkSum);
        scan_chunksums_kernel<<<1, 64, 0, stream>>>(chunkSum, chunkOff);
        chunk_scan_kernel<<<NCHUNKS, 256, 0, stream>>>(deg, chunkOff, start, cursor);
        csr_fill_kernel<<<eblocks, 256, 0, stream>>>(src, dst, cursor, csr_src);
        gcn_gather_kernel<<<(N_NODES + 3) / 4, 256, 0, stream>>>(h, start, csr_src, out);
    } else {
        hipMemsetAsync(out, 0, (size_t)out_size * sizeof(float), stream);
        gcn_scatter_kernel<<<(N_EDGES + 3) / 4, 256, 0, stream>>>(h, src, dst, out);
    }
}

// Round 8
// 262.948 us; speedup vs baseline: 1.9015x; 1.5040x over previous
//
#include <hip/hip_runtime.h>
#include <hip/hip_bf16.h>
#include <stdint.h>

#define N_NODES 100000
#define IN_F    512
#define OUT_F   256
#define N_EDGES 1600000

typedef __attribute__((ext_vector_type(4))) float f32x4;
typedef __attribute__((ext_vector_type(8))) short bf16x8;
typedef __attribute__((ext_vector_type(4))) uint32_t u32x4;

#define BM 128
#define BK 32
#define KT_TILES (IN_F / BK)             // 16
#define WFRAG_KT_STRIDE (16 * 16 * 32)   // 8192 elems per kt slab
#define EPS 66                            // epilogue LDS row stride (bf16)

#define NBUCK 196                         // ceil(100000/512) buckets of 512 nodes
#define SC_EDGES 8192                     // edges per bucket_scatter block

#define SCAN_CHUNK 4096
#define NCHUNKS ((N_NODES + SCAN_CHUNK - 1) / SCAN_CHUNK)   // 25

__device__ __forceinline__ float bf2f(uint16_t u) {
    union { uint32_t i; float f; } c; c.i = ((uint32_t)u) << 16; return c.f;
}
__device__ __forceinline__ uint16_t f2bf(float f) {
    union { float f; uint32_t i; } c; c.f = f;
    uint32_t x = c.i;
    return (uint16_t)((x + 0x7FFFu + ((x >> 16) & 1u)) >> 16);  // RNE
}
__device__ __forceinline__ uint32_t cvt_pk_bf16(float a, float b) {
    uint32_t r;
    asm("v_cvt_pk_bf16_f32 %0, %1, %2" : "=v"(r) : "v"(a), "v"(b));
    return r;
}
// async global->LDS, 16B per lane; LDS dest = wave-uniform base + lane*16
__device__ __forceinline__ void gload_lds16(const float* g, float* l) {
    __builtin_amdgcn_global_load_lds(
        (const __attribute__((address_space(1))) void*)g,
        (__attribute__((address_space(3))) void*)l, 16, 0, 0);
}

// ---------------- W -> bf16 fragment-order ----------------
__global__ __launch_bounds__(256) void w_frag_kernel(
    const float* __restrict__ W, uint16_t* __restrict__ w_frag)
{
    const int gid = blockIdx.x * 256 + threadIdx.x;   // 16384 groups of 8 elems
    if (gid >= 16384) return;
    const int kg = gid & 3, lrow = (gid >> 2) & 15, cg = (gid >> 6) & 15, kt = gid >> 10;
    const float* s = W + (size_t)(cg * 16 + lrow) * IN_F + kt * 32 + kg * 8;
    const f32x4 v0 = *(const f32x4*)s;
    const f32x4 v1 = *(const f32x4*)(s + 4);
    u32x4 c;
    c[0] = cvt_pk_bf16(v0[0], v0[1]);
    c[1] = cvt_pk_bf16(v0[2], v0[3]);
    c[2] = cvt_pk_bf16(v1[0], v1[1]);
    c[3] = cvt_pk_bf16(v1[2], v1[3]);
    *(u32x4*)(w_frag + (size_t)gid * 8) = c;
}

// ---------------- GEMM: h = bf16(feat @ W^T + b) (proven R7 version) ----------
__global__ __launch_bounds__(512) void gcn_gemm_kernel(
    const float* __restrict__ feat, const uint16_t* __restrict__ w_frag,
    const float* __restrict__ bias, uint16_t* __restrict__ h)
{
    __shared__ __align__(16) char smem_raw[2 * BM * BK * 4];   // 32 KB
    float (*At)[BM][BK] = (float (*)[BM][BK])smem_raw;

    const int m0 = blockIdx.x * BM;

    const int t    = threadIdx.x;
    const int wid  = t >> 6;
    const int lane = t & 63;
    const int wr   = wid >> 2, wc = wid & 3;   // 2x4 waves, 64x64 tile per wave
    const int lrow = lane & 15;
    const int kg   = lane >> 4;

    f32x4 acc[4][4] = {};

    const int r8 = lane >> 3;
    const int sp = lane & 7;
    const int sc = sp ^ r8;            // source-side swizzle
    const float* gsrc[2];
    #pragma unroll
    for (int i = 0; i < 2; ++i) {
        int grow = m0 + wid * 16 + i * 8 + r8;
        if (grow > N_NODES - 1) grow = N_NODES - 1;
        gsrc[i] = feat + (size_t)grow * IN_F + sc * 4;
    }

#define STAGE(KT, BUF)                                                     \
    do {                                                                   \
        gload_lds16(gsrc[0] + (KT) * BK, &At[BUF][wid * 16][0]);           \
        gload_lds16(gsrc[1] + (KT) * BK, &At[BUF][wid * 16 + 8][0]);       \
    } while (0)

    const uint16_t* wfp[4];
    #pragma unroll
    for (int n = 0; n < 4; ++n) {
        const int cg = wc * 4 + n;
        wfp[n] = w_frag + ((size_t)cg * 16 + lrow) * 32 + kg * 8;
    }

    bf16x8 bfr[2][4];

    STAGE(0, 0);
    #pragma unroll
    for (int n = 0; n < 4; ++n) bfr[0][n] = *(const bf16x8*)(wfp[n]);
    __syncthreads();

    const int p0 = (2 * kg) ^ (lrow & 7);   // read-side swizzle
    const int p1 = p0 ^ 1;

    #pragma unroll
    for (int kt = 0; kt < KT_TILES; ++kt) {
        const int cur = kt & 1, nxt = cur ^ 1;
        if (kt + 1 < KT_TILES) {
            STAGE(kt + 1, nxt);
            #pragma unroll
            for (int n = 0; n < 4; ++n)
                bfr[nxt][n] = *(const bf16x8*)(wfp[n] + (size_t)(kt + 1) * WFRAG_KT_STRIDE);
        }
        bf16x8 af[4];
        #pragma unroll
        for (int m = 0; m < 4; ++m) {
            const int row = wr * 64 + m * 16 + lrow;
            const f32x4 v0 = *(const f32x4*)&At[cur][row][p0 * 4];
            const f32x4 v1 = *(const f32x4*)&At[cur][row][p1 * 4];
            union { bf16x8 v; uint32_t u[4]; } c_;
            c_.u[0] = cvt_pk_bf16(v0[0], v0[1]);
            c_.u[1] = cvt_pk_bf16(v0[2], v0[3]);
            c_.u[2] = cvt_pk_bf16(v1[0], v1[1]);
            c_.u[3] = cvt_pk_bf16(v1[2], v1[3]);
            af[m] = c_.v;
        }
        #pragma unroll
        for (int m = 0; m < 4; ++m)
            #pragma unroll
            for (int n = 0; n < 4; ++n)
                acc[m][n] = __builtin_amdgcn_mfma_f32_16x16x32_bf16(
                    af[m], bfr[cur][n], acc[m][n], 0, 0, 0);
        if (kt + 1 < KT_TILES) __syncthreads();
    }
#undef STAGE

    __syncthreads();

    uint16_t* ep = (uint16_t*)smem_raw;
    const int wbase = wid * (16 * EPS);
    float bv[4];
    #pragma unroll
    for (int n = 0; n < 4; ++n) bv[n] = bias[wc * 64 + n * 16 + lrow];

    #pragma unroll
    for (int m = 0; m < 4; ++m) {
        #pragma unroll
        for (int n = 0; n < 4; ++n)
            #pragma unroll
            for (int j = 0; j < 4; ++j)
                ep[wbase + (kg * 4 + j) * EPS + n * 16 + lrow] = f2bf(acc[m][n][j] + bv[n]);
        __syncthreads();
        #pragma unroll
        for (int g = 0; g < 4; ++g) {
            const int r16  = g * 4 + (lane >> 4);
            const int cidx = (lane & 15) * 4;
            const int ib = wbase + r16 * EPS + cidx;
            uint2 v;
            v.x = *(const uint32_t*)&ep[ib];
            v.y = *(const uint32_t*)&ep[ib + 2];
            const int row = m0 + wr * 64 + m * 16 + r16;
            if (row < N_NODES)
                *(uint2*)(h + (size_t)row * OUT_F + wc * 64 + cidx) = v;
        }
        __syncthreads();
    }
}

// ================= bucketed CSR build (new path) =================
// pass 1: per-bucket edge counts (LDS-aggregated)
__global__ __launch_bounds__(256) void bucket_count_kernel(
    const int* __restrict__ dst, int* __restrict__ bucket_count)
{
    __shared__ int bh[NBUCK];
    for (int i = threadIdx.x; i < NBUCK; i += 256) bh[i] = 0;
    __syncthreads();
    const int base = blockIdx.x * SC_EDGES;
    #pragma unroll
    for (int k = 0; k < SC_EDGES / 256; ++k) {
        const int e = base + k * 256 + threadIdx.x;
        if (e < N_EDGES) atomicAdd(&bh[dst[e] >> 9], 1);
    }
    __syncthreads();
    for (int i = threadIdx.x; i < NBUCK; i += 256)
        if (bh[i]) atomicAdd(&bucket_count[i], bh[i]);
}

// pass 2: exclusive scan of bucket counts -> base + cursor
__global__ void bucket_scan_kernel(const int* __restrict__ bucket_count,
                                   int* __restrict__ bucket_base,
                                   int* __restrict__ bucket_cursor)
{
    __shared__ int sc[256];
    const int t = threadIdx.x;
    const int v = (t < NBUCK) ? bucket_count[t] : 0;
    int x = v;
    sc[t] = x; __syncthreads();
    for (int off = 1; off < 256; off <<= 1) {
        const int y = (t >= off) ? sc[t - off] : 0;
        __syncthreads();
        x += y; sc[t] = x;
        __syncthreads();
    }
    if (t < NBUCK) {
        const int ex = x - v;
        bucket_base[t] = ex;
        bucket_cursor[t] = ex;
    }
    if (t == 0) bucket_base[NBUCK] = N_EDGES;
}

// pass 3: scatter packed (src<<9 | dst&511) into bucket-major order.
// Block reserves per-bucket ranges with ONE global atomic per bucket.
__global__ __launch_bounds__(256) void bucket_scatter_kernel(
    const int* __restrict__ src, const int* __restrict__ dst,
    int* __restrict__ bucket_cursor, uint32_t* __restrict__ pairs)
{
    __shared__ int bh[NBUCK];
    __shared__ int bbase[NBUCK];
    for (int i = threadIdx.x; i < NBUCK; i += 256) bh[i] = 0;
    __syncthreads();
    const int base = blockIdx.x * SC_EDGES;
    uint32_t pk[SC_EDGES / 256];
    int      bk[SC_EDGES / 256];
    #pragma unroll
    for (int k = 0; k < SC_EDGES / 256; ++k) {
        const int e = base + k * 256 + threadIdx.x;
        if (e < N_EDGES) {
            const int d = dst[e], s = src[e];
            bk[k] = d >> 9;
            pk[k] = ((uint32_t)s << 9) | (uint32_t)(d & 511);
            atomicAdd(&bh[bk[k]], 1);
        } else {
            bk[k] = -1; pk[k] = 0;
        }
    }
    __syncthreads();
    for (int i = threadIdx.x; i < NBUCK; i += 256) {
        const int c = bh[i];
        bbase[i] = c ? atomicAdd(&bucket_cursor[i], c) : 0;
        bh[i] = 0;
    }
    __syncthreads();
    #pragma unroll
    for (int k = 0; k < SC_EDGES / 256; ++k) {
        if (bk[k] >= 0) {
            const int r = atomicAdd(&bh[bk[k]], 1);
            pairs[bbase[bk[k]] + r] = pk[k];
        }
    }
}

// pass 4: per-bucket counting sort -> start[] + csr_src (block-local region)
__global__ __launch_bounds__(256) void bucket_sort_kernel(
    const uint32_t* __restrict__ pairs, const int* __restrict__ bucket_base,
    int* __restrict__ start, int* __restrict__ csr_src)
{
    __shared__ int hist[512];
    __shared__ int tsum[256];
    const int b = blockIdx.x;
    const int t = threadIdx.x;
    const int ebeg = bucket_base[b], eend = bucket_base[b + 1];
    hist[t] = 0; hist[t + 256] = 0;
    __syncthreads();
    for (int i = ebeg + t; i < eend; i += 256)
        atomicAdd(&hist[pairs[i] & 511], 1);
    __syncthreads();
    const int c0 = hist[2 * t], c1 = hist[2 * t + 1];
    int x = c0 + c1;
    tsum[t] = x; __syncthreads();
    for (int off = 1; off < 256; off <<= 1) {
        const int y = (t >= off) ? tsum[t - off] : 0;
        __syncthreads();
        x += y; tsum[t] = x;
        __syncthreads();
    }
    const int ex = x - (c0 + c1);     // exclusive prefix over thread pairs
    __syncthreads();                  // all c0/c1 reads done before overwrite
    hist[2 * t] = ex;
    hist[2 * t + 1] = ex + c0;
    const int nb0 = b << 9;
    if (nb0 + 2 * t < N_NODES)     start[nb0 + 2 * t]     = ebeg + ex;
    if (nb0 + 2 * t + 1 < N_NODES) start[nb0 + 2 * t + 1] = ebeg + ex + c0;
    __syncthreads();
    for (int i = ebeg + t; i < eend; i += 256) {
        const uint32_t p = pairs[i];
        const int pos = ebeg + atomicAdd(&hist[p & 511], 1);
        csr_src[pos] = (int)(p >> 9);
    }
}

// ---------------- legacy CSR build (fallback if ws too small) ----------------
__global__ __launch_bounds__(256) void hist_kernel(
    const int* __restrict__ dst, int* __restrict__ deg)
{
    const int e = blockIdx.x * 256 + threadIdx.x;
    if (e < N_EDGES) atomicAdd(&deg[dst[e]], 1);
}

__global__ __launch_bounds__(256) void chunk_reduce_kernel(
    const int* __restrict__ deg, int* __restrict__ chunkSum)
{
    __shared__ int red[256];
    const int b = blockIdx.x, t = threadIdx.x;
    const int base = b * SCAN_CHUNK;
    int s = 0;
    #pragma unroll
    for (int i = 0; i < 16; ++i) {
        const int idx = base + t * 16 + i;
        s += (idx < N_NODES) ? deg[idx] : 0;
    }
    red[t] = s;
    __syncthreads();
    for (int off = 128; off > 0; off >>= 1) {
        if (t < off) red[t] += red[t + off];
        __syncthreads();
    }
    if (t == 0) chunkSum[b] = red[0];
}

__global__ void scan_chunksums_kernel(const int* __restrict__ chunkSum,
                                      int* __restrict__ chunkOff)
{
    if (threadIdx.x == 0 && blockIdx.x == 0) {
        int acc = 0;
        for (int i = 0; i < NCHUNKS; ++i) { chunkOff[i] = acc; acc += chunkSum[i]; }
    }
}

__global__ __launch_bounds__(256) void chunk_scan_kernel(
    const int* __restrict__ deg, const int* __restrict__ chunkOff,
    int* __restrict__ start, int* __restrict__ cursor)
{
    __shared__ int tsum[256];
    const int b = blockIdx.x, t = threadIdx.x;
    const int base = b * SCAN_CHUNK;
    int vals[16];
    int s = 0;
    #pragma unroll
    for (int i = 0; i < 16; ++i) {
        const int idx = base + t * 16 + i;
        const int v = (idx < N_NODES) ? deg[idx] : 0;
        vals[i] = s;
        s += v;
    }
    int x = s;
    tsum[t] = x;
    __syncthreads();
    #pragma unroll
    for (int off = 1; off < 256; off <<= 1) {
        const int y = (t >= off) ? tsum[t - off] : 0;
        __syncthreads();
        x += y;
        tsum[t] = x;
        __syncthreads();
    }
    const int thread_off = chunkOff[b] + (t == 0 ? 0 : tsum[t - 1]);
    #pragma unroll
    for (int i = 0; i < 16; ++i) {
        const int idx = base + t * 16 + i;
        if (idx < N_NODES) {
            const int st = thread_off + vals[i];
            start[idx] = st;
            cursor[idx] = st;
        }
    }
}

__global__ __launch_bounds__(256) void csr_fill_kernel(
    const int* __restrict__ src, const int* __restrict__ dst,
    int* __restrict__ cursor, int* __restrict__ csr_src)
{
    const int e = blockIdx.x * 256 + threadIdx.x;
    if (e < N_EDGES) {
        const int d = dst[e];
        const int p = atomicAdd(&cursor[d], 1);
        csr_src[p] = src[e];
    }
}

// ---------------- gather: one wave per dst node, atomic-free ----------------
__global__ __launch_bounds__(256) void gcn_gather_kernel(
    const uint16_t* __restrict__ h, const int* __restrict__ start,
    const int* __restrict__ csr_src, float* __restrict__ out)
{
    const int n = blockIdx.x * 4 + (threadIdx.x >> 6);
    if (n >= N_NODES) return;
    const int lane = threadIdx.x & 63;
    const int beg = start[n];
    const int end = (n == N_NODES - 1) ? N_EDGES : start[n + 1];

    float a0 = 0.f, a1 = 0.f, a2 = 0.f, a3 = 0.f;
    int j = beg;
    for (; j + 3 < end; j += 4) {
        const int s0 = csr_src[j];
        const int s1 = csr_src[j + 1];
        const int s2 = csr_src[j + 2];
        const int s3 = csr_src[j + 3];
        const ushort4 v0 = *((const ushort4*)(h + (size_t)s0 * OUT_F) + lane);
        const ushort4 v1 = *((const ushort4*)(h + (size_t)s1 * OUT_F) + lane);
        const ushort4 v2 = *((const ushort4*)(h + (size_t)s2 * OUT_F) + lane);
        const ushort4 v3 = *((const ushort4*)(h + (size_t)s3 * OUT_F) + lane);
        a0 += bf2f(v0.x); a1 += bf2f(v0.y); a2 += bf2f(v0.z); a3 += bf2f(v0.w);
        a0 += bf2f(v1.x); a1 += bf2f(v1.y); a2 += bf2f(v1.z); a3 += bf2f(v1.w);
        a0 += bf2f(v2.x); a1 += bf2f(v2.y); a2 += bf2f(v2.z); a3 += bf2f(v2.w);
        a0 += bf2f(v3.x); a1 += bf2f(v3.y); a2 += bf2f(v3.z); a3 += bf2f(v3.w);
    }
    for (; j < end; ++j) {
        const int s0 = csr_src[j];
        const ushort4 v0 = *((const ushort4*)(h + (size_t)s0 * OUT_F) + lane);
        a0 += bf2f(v0.x); a1 += bf2f(v0.y); a2 += bf2f(v0.z); a3 += bf2f(v0.w);
    }
    f32x4 o; o[0] = a0; o[1] = a1; o[2] = a2; o[3] = a3;
    *((f32x4*)(out + (size_t)n * OUT_F) + lane) = o;
}

// ---------------- fallback atomic scatter (tiny ws) ----------------
__global__ __launch_bounds__(256) void gcn_scatter_kernel(
    const uint16_t* __restrict__ h, const int* __restrict__ src,
    const int* __restrict__ dst, float* __restrict__ out)
{
    const int e = (blockIdx.x << 2) | (threadIdx.x >> 6);
    if (e >= N_EDGES) return;
    const int lane = threadIdx.x & 63;
    const int s = src[e];
    const int d = dst[e];
    const ushort4 v = *((const ushort4*)(h + (size_t)s * OUT_F) + lane);
    float* op = out + (size_t)d * OUT_F + (lane << 2);
    unsafeAtomicAdd(op + 0, bf2f(v.x));
    unsafeAtomicAdd(op + 1, bf2f(v.y));
    unsafeAtomicAdd(op + 2, bf2f(v.z));
    unsafeAtomicAdd(op + 3, bf2f(v.w));
}

static inline size_t align256(size_t x) { return (x + 255) & ~(size_t)255; }

extern "C" void kernel_launch(void* const* d_in, const int* in_sizes, int n_in,
                              void* d_out, int out_size, void* d_ws, size_t ws_size,
                              hipStream_t stream) {
    const float* feat = (const float*)d_in[0];
    const float* W    = (const float*)d_in[1];
    const float* bias = (const float*)d_in[2];
    const int*   src  = (const int*)d_in[3];
    const int*   dst  = (const int*)d_in[4];
    float*       out  = (float*)d_out;

    char* ws = (char*)d_ws;

    // ---- new (bucketed) layout ----
    size_t off = 0;
    uint16_t* h       = (uint16_t*)(ws + off); off = align256(off + (size_t)N_NODES * OUT_F * 2);
    uint16_t* w_frag  = (uint16_t*)(ws + off); off = align256(off + (size_t)OUT_F * IN_F * 2);
    int* start        = (int*)(ws + off);      off = align256(off + (size_t)N_NODES * 4);
    int* bucket_count = (int*)(ws + off);      off = align256(off + (size_t)NBUCK * 4);
    int* bucket_base  = (int*)(ws + off);      off = align256(off + (size_t)(NBUCK + 1) * 4);
    int* bucket_cursor= (int*)(ws + off);      off = align256(off + (size_t)NBUCK * 4);
    uint32_t* pairs   = (uint32_t*)(ws + off); off = align256(off + (size_t)N_EDGES * 4);
    int* csr_src      = (int*)(ws + off);      off = align256(off + (size_t)N_EDGES * 4);
    const bool bucket_ok = (off <= ws_size);

    const int mtiles = (N_NODES + BM - 1) / BM;  // 782
    const int scblocks = (N_EDGES + SC_EDGES - 1) / SC_EDGES;  // 196

    w_frag_kernel<<<64, 256, 0, stream>>>(W, w_frag);
    gcn_gemm_kernel<<<mtiles, 512, 0, stream>>>(feat, w_frag, bias, h);

    if (bucket_ok) {
        hipMemsetAsync(bucket_count, 0, (size_t)NBUCK * 4, stream);
        bucket_count_kernel<<<scblocks, 256, 0, stream>>>(dst, bucket_count);
        bucket_scan_kernel<<<1, 256, 0, stream>>>(bucket_count, bucket_base, bucket_cursor);
        bucket_scatter_kernel<<<scblocks, 256, 0, stream>>>(src, dst, bucket_cursor, pairs);
        bucket_sort_kernel<<<NBUCK, 256, 0, stream>>>(pairs, bucket_base, start, csr_src);
        gcn_gather_kernel<<<(N_NODES + 3) / 4, 256, 0, stream>>>(h, start, csr_src, out);
        return;
    }

    // ---- legacy layout / path ----
    off = 0;
    h            = (uint16_t*)(ws + off); off = align256(off + (size_t)N_NODES * OUT_F * 2);
    w_frag       = (uint16_t*)(ws + off); off = align256(off + (size_t)OUT_F * IN_F * 2);
    int* deg     = (int*)(ws + off);      off = align256(off + (size_t)N_NODES * 4);
    start        = (int*)(ws + off);      off = align256(off + (size_t)N_NODES * 4);
    int* cursor  = (int*)(ws + off);      off = align256(off + (size_t)N_NODES * 4);
    int* chunkSum= (int*)(ws + off);      off = align256(off + (size_t)NCHUNKS * 4);
    int* chunkOff= (int*)(ws + off);      off = align256(off + (size_t)NCHUNKS * 4);
    csr_src      = (int*)(ws + off);      off = align256(off + (size_t)N_EDGES * 4);
    const bool csr_ok = (off <= ws_size);

    if (csr_ok) {
        hipMemsetAsync(deg, 0, (size_t)N_NODES * 4, stream);
        const int eblocks = (N_EDGES + 255) / 256;
        hist_kernel<<<eblocks, 256, 0, stream>>>(dst, deg);
        chunk_reduce_kernel<<<NCHUNKS, 256, 0, stream>>>(deg, chunkSum);
        scan_chunksums_kernel<<<1, 64, 0, stream>>>(chunkSum, chunkOff);
        chunk_scan_kernel<<<NCHUNKS, 256, 0, stream>>>(deg, chunkOff, start, cursor);
        csr_fill_kernel<<<eblocks, 256, 0, stream>>>(src, dst, cursor, csr_src);
        gcn_gather_kernel<<<(N_NODES + 3) / 4, 256, 0, stream>>>(h, start, csr_src, out);
    } else {
        hipMemsetAsync(out, 0, (size_t)out_size * sizeof(float), stream);
        gcn_scatter_kernel<<<(N_EDGES + 3) / 4, 256, 0, stream>>>(h, src, dst, out);
    }
}